// Round 11
// baseline (440.315 us; speedup 1.0000x reference)
//
#include <hip/hip_runtime.h>

// WindowAttention3D: B=1024, N1=256, N2=128, C=128, NH=4, hd=32, nW=64
// out = [x (1024*256*128 f32)] ++ [attn (1024*4*256*128 f32)]
// R11: drop bm table (on-the-fly bias(512KB,L2-hot) + mask(8MB, 4x intra-block
//      reuse)); XCD-cohort block mapping (16 b-blocks of one (wdw,q0) share an
//      XCD's L2); V loads hoisted above softmax.

typedef __attribute__((ext_vector_type(8))) short s16x8;
typedef __attribute__((ext_vector_type(4))) short s16x4;
typedef __attribute__((ext_vector_type(4))) float f32x4;

static __device__ __forceinline__ unsigned short f2bf(float f) {
  union { float f; unsigned u; } v; v.f = f;
  unsigned r = v.u + 0x7FFFu + ((v.u >> 16) & 1u);
  return (unsigned short)(r >> 16);
}

static __device__ __forceinline__ s16x8 cvt8(f32x4 a0, f32x4 a1) {
  s16x8 r;
  r[0] = (short)f2bf(a0[0]); r[1] = (short)f2bf(a0[1]);
  r[2] = (short)f2bf(a0[2]); r[3] = (short)f2bf(a0[3]);
  r[4] = (short)f2bf(a1[0]); r[5] = (short)f2bf(a1[1]);
  r[6] = (short)f2bf(a1[2]); r[7] = (short)f2bf(a1[3]);
  return r;
}

// ---------------- prep: weights->bf16, bias gather (512 KB) ----------------
// biasT[h][q][n2] = rpb[rel_index[q][n2]][h]
__global__ void kw_prep(const float* __restrict__ qw, const float* __restrict__ kvw,
                        const float* __restrict__ pw, const float* __restrict__ rpb,
                        const int* __restrict__ relidx,
                        unsigned short* __restrict__ qwb, unsigned short* __restrict__ kvwb,
                        unsigned short* __restrict__ pwb, float* __restrict__ biasT) {
  int tid = blockIdx.x * 256 + threadIdx.x;
  int stride = gridDim.x * 256;
  for (int i = tid; i < 65536; i += stride) {
    if (i < 16384)      qwb[i] = f2bf(qw[i]);
    else if (i < 49152) kvwb[i - 16384] = f2bf(kvw[i - 16384]);
    else                pwb[i - 49152] = f2bf(pw[i - 49152]);
  }
  for (int i = tid; i < 32768; i += stride) {
    int rel = relidx[i];
    float4 t = *(const float4*)(rpb + rel * 4);
    biasT[i]          = t.x;
    biasT[32768 + i]  = t.y;
    biasT[65536 + i]  = t.z;
    biasT[98304 + i]  = t.w;
  }
}

// ---------------- kv projection: kws[b][h][n2][32], vT[b][h][dh][n2] ----------------
__global__ __launch_bounds__(256) void kkv(const float* __restrict__ kv,
    const unsigned short* __restrict__ kvwb, const float* __restrict__ kvb,
    unsigned short* __restrict__ kws, unsigned short* __restrict__ vT) {
  __shared__ unsigned short oK[64][136];
  __shared__ unsigned short oV[128][72];
  int b = blockIdx.x >> 1, r0 = (blockIdx.x & 1) << 6;
  int t = threadIdx.x;
  int w = t >> 6, l = t & 63, lm = l & 15, lg = l >> 4;
  const float* arow = kv + (size_t)(b * 128 + r0 + w * 16 + lm) * 128;
  f32x4 acc[16];
#pragma unroll
  for (int i = 0; i < 16; ++i) acc[i] = (f32x4){0.f, 0.f, 0.f, 0.f};
#pragma unroll
  for (int kk = 0; kk < 4; ++kk) {
    f32x4 a0 = __builtin_nontemporal_load((const f32x4*)(arow + kk * 32 + lg * 8));
    f32x4 a1 = __builtin_nontemporal_load((const f32x4*)(arow + kk * 32 + lg * 8 + 4));
    s16x8 a = cvt8(a0, a1);
#pragma unroll
    for (int ct = 0; ct < 16; ++ct) {
      s16x8 bf = *(const s16x8*)(kvwb + (ct * 16 + lm) * 128 + kk * 32 + lg * 8);
      acc[ct] = __builtin_amdgcn_mfma_f32_16x16x32_bf16(a, bf, acc[ct], 0, 0, 0);
    }
  }
#pragma unroll
  for (int ct = 0; ct < 16; ++ct) {
    int col = ct * 16 + lm;
    float bb = kvb[col];
    if (col < 128) {
#pragma unroll
      for (int r = 0; r < 4; ++r)
        oK[w * 16 + lg * 4 + r][col] = f2bf(acc[ct][r] + bb);
    } else {
      int d = col - 128;
      s16x4 pk;
#pragma unroll
      for (int r = 0; r < 4; ++r) pk[r] = (short)f2bf(acc[ct][r] + bb);
      *(s16x4*)&oV[d][w * 16 + lg * 4] = pk;
    }
  }
  __syncthreads();
  {
    int o = t * 8, row = o >> 5, cs = o & 31;
#pragma unroll
    for (int h = 0; h < 4; ++h) {
      s16x8 v = *(const s16x8*)&oK[row][h * 32 + cs];
      *(s16x8*)(kws + ((size_t)(b * 4 + h) * 128 + r0 + row) * 32 + cs) = v;
    }
  }
#pragma unroll
  for (int i = 0; i < 4; ++i) {
    int o = (t + i * 256) * 8;
    int d = o >> 6, ns = o & 63;
    s16x8 v = *(const s16x8*)&oV[d][ns];
    *(s16x8*)(vT + ((size_t)b * 128 + d) * 128 + r0 + ns) = v;
  }
}

// ---------------- fused: q-proj + attention + out-proj per (b, 64 q rows) ----------------
__global__ __launch_bounds__(256, 3) void kfused(const float* __restrict__ q,
    const unsigned short* __restrict__ qwb, const float* __restrict__ qb,
    const unsigned short* __restrict__ kws, const unsigned short* __restrict__ vT,
    const float* __restrict__ biasT, const float* __restrict__ mask,
    const unsigned short* __restrict__ pwb, const float* __restrict__ pb,
    float* __restrict__ attn_out, float* __restrict__ xout) {
  __shared__ unsigned short qhL[64][136];   // qh tile, all heads
  __shared__ unsigned short XL[64][136];    // attention output tile, all heads
  __shared__ float scratch[4][1088] __attribute__((aligned(16))); // per-wave aSt[16][68]
  int bid = blockIdx.x;
  // XCD-cohort mapping: all 16 b-blocks of group g=(wdw,q0) satisfy bid%8==g%8
  // -> same XCD -> shared mask/bias slices stay L2-resident.
  int c = bid & 7, j = (bid >> 3) & 15, hi = bid >> 7;
  int g = hi * 8 + c;
  int wdw = g >> 2, q0 = (g & 3) << 6;
  int b = wdw + 64 * j;
  int t = threadIdx.x;
  int w = t >> 6, l = t & 63, lm = l & 15, lg = l >> 4;
  float* aSt = scratch[w];                  // [16][68] f32
  const f32x4 zero = {0.f, 0.f, 0.f, 0.f};

  // ---- Phase 1: q-proj, wave w -> rows w*16..w*16+15 ----
  {
    const float* arow = q + (size_t)(b * 256 + q0 + w * 16 + lm) * 128;
    f32x4 acc[8];
#pragma unroll
    for (int i = 0; i < 8; ++i) acc[i] = zero;
#pragma unroll
    for (int kk = 0; kk < 4; ++kk) {
      f32x4 a0 = __builtin_nontemporal_load((const f32x4*)(arow + kk * 32 + lg * 8));
      f32x4 a1 = __builtin_nontemporal_load((const f32x4*)(arow + kk * 32 + lg * 8 + 4));
      s16x8 a = cvt8(a0, a1);
#pragma unroll
      for (int ct = 0; ct < 8; ++ct) {
        s16x8 bf = *(const s16x8*)(qwb + (ct * 16 + lm) * 128 + kk * 32 + lg * 8);
        acc[ct] = __builtin_amdgcn_mfma_f32_16x16x32_bf16(a, bf, acc[ct], 0, 0, 0);
      }
    }
    const float SC = 0.17677669529663687f;   // 32^-0.5
#pragma unroll
    for (int ct = 0; ct < 8; ++ct) {
      int col = ct * 16 + lm;
      float bb = qb[col];
#pragma unroll
      for (int r2 = 0; r2 < 4; ++r2)
        qhL[w * 16 + lg * 4 + r2][col] = f2bf((acc[ct][r2] + bb) * SC);
    }
  }
  __syncthreads();

  // ---- Phase 2: attention, wave w = head h, 4 subtiles of 16 q-rows ----
  {
    int h = w;
    const unsigned short* ksrc = kws + (size_t)(b * 4 + h) * 4096;
    const unsigned short* vsrc = vT + (size_t)(b * 4 + h) * 4096;
    const float* biash = biasT + (size_t)h * 32768;
    const float* maskw = mask + (size_t)wdw * 32768;
    float* attnh = attn_out + ((size_t)(b * 4 + h) * 256 + q0) * 128;
    for (int qt = 0; qt < 4; ++qt) {
      int qg = q0 + qt * 16 + lm;
      // V loads hoisted: latency hides under QK^T + softmax
      s16x8 av[8];
#pragma unroll
      for (int kk = 0; kk < 4; ++kk)
#pragma unroll
        for (int cd = 0; cd < 2; ++cd)
          av[kk * 2 + cd] = *(const s16x8*)(vsrc + (cd * 16 + lm) * 128 + kk * 32 + lg * 8);
      s16x8 bq = *(const s16x8*)&qhL[qt * 16 + lm][h * 32 + lg * 8];
      f32x4 S[8];  // S^T: row n2 = ct*16+lg*4+r, col q = lm
#pragma unroll
      for (int ct = 0; ct < 8; ++ct) {
        s16x8 ak = *(const s16x8*)(ksrc + (ct * 16 + lm) * 32 + lg * 8);
        S[ct] = __builtin_amdgcn_mfma_f32_16x16x32_bf16(ak, bq, zero, 0, 0, 0);
      }
      float m = -1e30f;
#pragma unroll
      for (int ct = 0; ct < 8; ++ct) {
        float4 bv = *(const float4*)(biash + (size_t)qg * 128 + ct * 16 + lg * 4);
        float4 mv = *(const float4*)(maskw + (size_t)qg * 128 + ct * 16 + lg * 4);
        S[ct][0] += bv.x + mv.x; S[ct][1] += bv.y + mv.y;
        S[ct][2] += bv.z + mv.z; S[ct][3] += bv.w + mv.w;
        m = fmaxf(m, fmaxf(fmaxf(S[ct][0], S[ct][1]), fmaxf(S[ct][2], S[ct][3])));
      }
      m = fmaxf(m, __shfl_xor(m, 16));
      m = fmaxf(m, __shfl_xor(m, 32));
      float s = 0.f;
#pragma unroll
      for (int ct = 0; ct < 8; ++ct) {
#pragma unroll
        for (int r2 = 0; r2 < 4; ++r2) { S[ct][r2] = __expf(S[ct][r2] - m); s += S[ct][r2]; }
      }
      s += __shfl_xor(s, 16);
      s += __shfl_xor(s, 32);
      float inv = 1.0f / s;
      float* adst = attnh + qt * 16 * 128;
      s16x8 pfrag[4];
#pragma unroll
      for (int half = 0; half < 2; ++half) {
#pragma unroll
        for (int cc = 0; cc < 4; ++cc) {
          int ct = half * 4 + cc;
          f32x4 pv = { S[ct][0] * inv, S[ct][1] * inv, S[ct][2] * inv, S[ct][3] * inv };
          *(f32x4*)(aSt + lm * 68 + cc * 16 + lg * 4) = pv;
        }
#pragma unroll
        for (int i = 0; i < 4; ++i) {
          int o = l * 4 + i * 256;
          int row = o >> 6, col = o & 63;
          f32x4 v = *(const f32x4*)(aSt + row * 68 + col);
          __builtin_nontemporal_store(v, (f32x4*)(adst + row * 128 + half * 64 + col));
        }
#pragma unroll
        for (int k2 = 0; k2 < 2; ++k2) {
          const float* pp = aSt + lm * 68 + k2 * 32 + lg * 8;
          pfrag[half * 2 + k2] = cvt8(*(const f32x4*)pp, *(const f32x4*)(pp + 4));
        }
      }
      // PV (V already in registers)
      f32x4 O[2];
      O[0] = zero; O[1] = zero;
#pragma unroll
      for (int kk = 0; kk < 4; ++kk)
#pragma unroll
        for (int cd = 0; cd < 2; ++cd)
          O[cd] = __builtin_amdgcn_mfma_f32_16x16x32_bf16(av[kk * 2 + cd], pfrag[kk], O[cd], 0, 0, 0);
#pragma unroll
      for (int cd = 0; cd < 2; ++cd) {
        s16x4 pk;
#pragma unroll
        for (int r2 = 0; r2 < 4; ++r2) pk[r2] = (short)f2bf(O[cd][r2]);
        *(s16x4*)&XL[qt * 16 + lm][h * 32 + cd * 16 + lg * 4] = pk;
      }
    }
  }
  __syncthreads();

  // ---- Phase 3: out-proj, wave w -> rows w*16..w*16+15 ----
  {
    f32x4 acc[8];
#pragma unroll
    for (int i = 0; i < 8; ++i) acc[i] = zero;
#pragma unroll
    for (int kk = 0; kk < 4; ++kk) {
      s16x8 a = *(const s16x8*)&XL[w * 16 + lm][kk * 32 + lg * 8];
#pragma unroll
      for (int ct = 0; ct < 8; ++ct) {
        s16x8 bf = *(const s16x8*)(pwb + (ct * 16 + lm) * 128 + kk * 32 + lg * 8);
        acc[ct] = __builtin_amdgcn_mfma_f32_16x16x32_bf16(a, bf, acc[ct], 0, 0, 0);
      }
    }
#pragma unroll
    for (int ct = 0; ct < 8; ++ct) {
      int col = ct * 16 + lm;
      float bb = pb[col];
#pragma unroll
      for (int r2 = 0; r2 < 4; ++r2) acc[ct][r2] += bb;
    }
    float* xdst = xout + ((size_t)b * 256 + q0 + w * 16) * 128;
#pragma unroll
    for (int half = 0; half < 2; ++half) {
#pragma unroll
      for (int cc = 0; cc < 4; ++cc) {
        int ct = half * 4 + cc;
#pragma unroll
        for (int r2 = 0; r2 < 4; ++r2)
          aSt[(lg * 4 + r2) * 68 + cc * 16 + lm] = acc[ct][r2];
      }
#pragma unroll
      for (int i = 0; i < 4; ++i) {
        int o = l * 4 + i * 256;
        int row = o >> 6, col = o & 63;
        f32x4 v = *(const f32x4*)(aSt + row * 68 + col);
        __builtin_nontemporal_store(v, (f32x4*)(xdst + row * 128 + half * 64 + col));
      }
    }
  }
}

extern "C" void kernel_launch(void* const* d_in, const int* in_sizes, int n_in,
                              void* d_out, int out_size, void* d_ws, size_t ws_size,
                              hipStream_t stream) {
  const float* q    = (const float*)d_in[0];
  const float* kv   = (const float*)d_in[1];
  const float* mask = (const float*)d_in[2];
  const float* qw   = (const float*)d_in[3];
  const float* qb   = (const float*)d_in[4];
  const float* kvw  = (const float*)d_in[5];
  const float* kvb  = (const float*)d_in[6];
  const float* pw   = (const float*)d_in[7];
  const float* pb   = (const float*)d_in[8];
  const float* rpb  = (const float*)d_in[9];
  const int* relidx = (const int*)d_in[10];

  float* xout = (float*)d_out;
  float* attn = xout + (size_t)1024 * 256 * 128;   // 33,554,432

  char* ws = (char*)d_ws;
  unsigned short* qwb   = (unsigned short*)ws;                 // 32 KB
  unsigned short* kvwb  = (unsigned short*)(ws + 32768);       // 64 KB
  unsigned short* pwb   = (unsigned short*)(ws + 98304);       // 32 KB
  float*          biasT = (float*)(ws + 131072);               // 512 KB
  unsigned short* kws   = (unsigned short*)(ws + 655360);      // 32 MB
  unsigned short* vT    = kws + (size_t)16777216;              // 32 MB

  kw_prep<<<256, 256, 0, stream>>>(qw, kvw, pw, rpb, relidx, qwb, kvwb, pwb, biasT);
  kkv<<<2048, 256, 0, stream>>>(kv, kvwb, kvb, kws, vT);
  kfused<<<4096, 256, 0, stream>>>(q, qwb, qb, kws, vT, biasT, mask, pwb, pb, attn, xout);
}

// Round 12
// 418.930 us; speedup vs baseline: 1.0510x; 1.0510x over previous
//
#include <hip/hip_runtime.h>

// WindowAttention3D: B=1024, N1=256, N2=128, C=128, NH=4, hd=32, nW=64
// out = [x (1024*256*128 f32)] ++ [attn (1024*4*256*128 f32)]
// R12: latency-chain surgery in kfused: K/V hoisted to registers (qt-invariant),
//      bm register-prefetch distance 1, double-buffered LDS scratch,
//      lgkm-only barriers (attn NT stores drain under phase 3).

typedef __attribute__((ext_vector_type(8))) short s16x8;
typedef __attribute__((ext_vector_type(4))) short s16x4;
typedef __attribute__((ext_vector_type(4))) float f32x4;

static __device__ __forceinline__ unsigned short f2bf(float f) {
  union { float f; unsigned u; } v; v.f = f;
  unsigned r = v.u + 0x7FFFu + ((v.u >> 16) & 1u);
  return (unsigned short)(r >> 16);
}

static __device__ __forceinline__ s16x8 cvt8(f32x4 a0, f32x4 a1) {
  s16x8 r;
  r[0] = (short)f2bf(a0[0]); r[1] = (short)f2bf(a0[1]);
  r[2] = (short)f2bf(a0[2]); r[3] = (short)f2bf(a0[3]);
  r[4] = (short)f2bf(a1[0]); r[5] = (short)f2bf(a1[1]);
  r[6] = (short)f2bf(a1[2]); r[7] = (short)f2bf(a1[3]);
  return r;
}

// ---------------- prep: weights->bf16, combined bias+mask table ----------------
// bm[w][h][q][n2] = rpb[rel_index[q][n2]][h] + mask[w][q][n2]   (f32, 32 MB)
__global__ void kw_prep(const float* __restrict__ qw, const float* __restrict__ kvw,
                        const float* __restrict__ pw, const float* __restrict__ rpb,
                        const int* __restrict__ relidx, const float* __restrict__ mask,
                        unsigned short* __restrict__ qwb, unsigned short* __restrict__ kvwb,
                        unsigned short* __restrict__ pwb, float* __restrict__ bm) {
  int tid = blockIdx.x * 256 + threadIdx.x;
  int stride = gridDim.x * 256;
  for (int i = tid; i < 65536; i += stride) {
    if (i < 16384)      qwb[i] = f2bf(qw[i]);
    else if (i < 49152) kvwb[i - 16384] = f2bf(kvw[i - 16384]);
    else                pwb[i - 49152] = f2bf(pw[i - 49152]);
  }
  for (int i = tid; i < 2097152; i += stride) {
    int wdw = i >> 15, j = i & 32767;
    int rel = relidx[j];
    float4 tv = *(const float4*)(rpb + rel * 4);
    float mk = mask[i];
    float* d = bm + (size_t)(wdw * 4) * 32768 + j;
    d[0]      = tv.x + mk;
    d[32768]  = tv.y + mk;
    d[65536]  = tv.z + mk;
    d[98304]  = tv.w + mk;
  }
}

// ---------------- kv projection: kws[b][h][n2][32], vT[b][h][dh][n2] ----------------
__global__ __launch_bounds__(256) void kkv(const float* __restrict__ kv,
    const unsigned short* __restrict__ kvwb, const float* __restrict__ kvb,
    unsigned short* __restrict__ kws, unsigned short* __restrict__ vT) {
  __shared__ unsigned short oK[64][136];
  __shared__ unsigned short oV[128][72];
  int b = blockIdx.x >> 1, r0 = (blockIdx.x & 1) << 6;
  int t = threadIdx.x;
  int w = t >> 6, l = t & 63, lm = l & 15, lg = l >> 4;
  const float* arow = kv + (size_t)(b * 128 + r0 + w * 16 + lm) * 128;
  f32x4 acc[16];
#pragma unroll
  for (int i = 0; i < 16; ++i) acc[i] = (f32x4){0.f, 0.f, 0.f, 0.f};
#pragma unroll
  for (int kk = 0; kk < 4; ++kk) {
    f32x4 a0 = __builtin_nontemporal_load((const f32x4*)(arow + kk * 32 + lg * 8));
    f32x4 a1 = __builtin_nontemporal_load((const f32x4*)(arow + kk * 32 + lg * 8 + 4));
    s16x8 a = cvt8(a0, a1);
#pragma unroll
    for (int ct = 0; ct < 16; ++ct) {
      s16x8 bf = *(const s16x8*)(kvwb + (ct * 16 + lm) * 128 + kk * 32 + lg * 8);
      acc[ct] = __builtin_amdgcn_mfma_f32_16x16x32_bf16(a, bf, acc[ct], 0, 0, 0);
    }
  }
#pragma unroll
  for (int ct = 0; ct < 16; ++ct) {
    int col = ct * 16 + lm;
    float bb = kvb[col];
    if (col < 128) {
#pragma unroll
      for (int r = 0; r < 4; ++r)
        oK[w * 16 + lg * 4 + r][col] = f2bf(acc[ct][r] + bb);
    } else {
      int d = col - 128;
      s16x4 pk;
#pragma unroll
      for (int r = 0; r < 4; ++r) pk[r] = (short)f2bf(acc[ct][r] + bb);
      *(s16x4*)&oV[d][w * 16 + lg * 4] = pk;
    }
  }
  __syncthreads();
  {
    int o = t * 8, row = o >> 5, cs = o & 31;
#pragma unroll
    for (int h = 0; h < 4; ++h) {
      s16x8 v = *(const s16x8*)&oK[row][h * 32 + cs];
      *(s16x8*)(kws + ((size_t)(b * 4 + h) * 128 + r0 + row) * 32 + cs) = v;
    }
  }
#pragma unroll
  for (int i = 0; i < 4; ++i) {
    int o = (t + i * 256) * 8;
    int d = o >> 6, ns = o & 63;
    s16x8 v = *(const s16x8*)&oV[d][ns];
    *(s16x8*)(vT + ((size_t)b * 128 + d) * 128 + r0 + ns) = v;
  }
}

// ---------------- fused: q-proj + attention + out-proj per (b, 64 q rows) ----------------
__global__ __launch_bounds__(256, 2) void kfused(const float* __restrict__ q,
    const unsigned short* __restrict__ qwb, const float* __restrict__ qb,
    const unsigned short* __restrict__ kws, const unsigned short* __restrict__ vT,
    const float* __restrict__ bm, const unsigned short* __restrict__ pwb,
    const float* __restrict__ pb, float* __restrict__ attn_out,
    float* __restrict__ xout) {
  __shared__ unsigned short qhL[64][136];   // qh tile, all heads
  __shared__ unsigned short XL[64][136];    // attention output tile, all heads
  __shared__ float scratch[4][2176] __attribute__((aligned(16))); // per-wave 2x [16][68]
  int bid = blockIdx.x;
  // window-major ordering (R10): co-resident blocks share few bm windows
  int wdw = bid >> 6, rr = bid & 63;
  int b = wdw + (rr >> 2) * 64;
  int q0 = (rr & 3) << 6;
  int t = threadIdx.x;
  int w = t >> 6, l = t & 63, lm = l & 15, lg = l >> 4;
  const f32x4 zero = {0.f, 0.f, 0.f, 0.f};

  // ---- Phase 1: q-proj, wave w -> rows w*16..w*16+15 ----
  {
    const float* arow = q + (size_t)(b * 256 + q0 + w * 16 + lm) * 128;
    f32x4 acc[8];
#pragma unroll
    for (int i = 0; i < 8; ++i) acc[i] = zero;
#pragma unroll
    for (int kk = 0; kk < 4; ++kk) {
      f32x4 a0 = __builtin_nontemporal_load((const f32x4*)(arow + kk * 32 + lg * 8));
      f32x4 a1 = __builtin_nontemporal_load((const f32x4*)(arow + kk * 32 + lg * 8 + 4));
      s16x8 a = cvt8(a0, a1);
#pragma unroll
      for (int ct = 0; ct < 8; ++ct) {
        s16x8 bf = *(const s16x8*)(qwb + (ct * 16 + lm) * 128 + kk * 32 + lg * 8);
        acc[ct] = __builtin_amdgcn_mfma_f32_16x16x32_bf16(a, bf, acc[ct], 0, 0, 0);
      }
    }
    const float SC = 0.17677669529663687f;   // 32^-0.5
#pragma unroll
    for (int ct = 0; ct < 8; ++ct) {
      int col = ct * 16 + lm;
      float bb = qb[col];
#pragma unroll
      for (int r2 = 0; r2 < 4; ++r2)
        qhL[w * 16 + lg * 4 + r2][col] = f2bf((acc[ct][r2] + bb) * SC);
    }
  }
  asm volatile("s_waitcnt lgkmcnt(0)" ::: "memory");
  __builtin_amdgcn_s_barrier();

  // ---- Phase 2: attention, wave w = head h ----
  {
    int h = w;
    const unsigned short* ksrc = kws + (size_t)(b * 4 + h) * 4096;
    const unsigned short* vsrc = vT + (size_t)(b * 4 + h) * 4096;
    const float* bmh = bm + ((size_t)(wdw * 4 + h) * 256 + q0) * 128;
    float* attnh = attn_out + ((size_t)(b * 4 + h) * 256 + q0) * 128;
    float* aSt0 = scratch[w];
    float* aSt1 = scratch[w] + 1088;

    // K and V fragments are qt-invariant: load ONCE into registers
    s16x8 ak[8], av[8];
#pragma unroll
    for (int ct = 0; ct < 8; ++ct)
      ak[ct] = *(const s16x8*)(ksrc + (ct * 16 + lm) * 32 + lg * 8);
#pragma unroll
    for (int kk = 0; kk < 4; ++kk)
#pragma unroll
      for (int cd = 0; cd < 2; ++cd)
        av[kk * 2 + cd] = *(const s16x8*)(vsrc + (cd * 16 + lm) * 128 + kk * 32 + lg * 8);

    // bm double-buffered register prefetch (distance 1)
    f32x4 bmA[8], bmB[8];
#pragma unroll
    for (int ct = 0; ct < 8; ++ct)
      bmA[ct] = *(const f32x4*)(bmh + (size_t)lm * 128 + ct * 16 + lg * 4);

    auto body = [&](int qt, f32x4* bmc, f32x4* bmn, bool pre) {
      if (pre) {
#pragma unroll
        for (int ct = 0; ct < 8; ++ct)
          bmn[ct] = *(const f32x4*)(bmh + (size_t)((qt + 1) * 16 + lm) * 128 + ct * 16 + lg * 4);
      }
      s16x8 bq = *(const s16x8*)&qhL[qt * 16 + lm][h * 32 + lg * 8];
      f32x4 S[8];  // S^T: row n2 = ct*16+lg*4+r, col q = lm
#pragma unroll
      for (int ct = 0; ct < 8; ++ct)
        S[ct] = __builtin_amdgcn_mfma_f32_16x16x32_bf16(ak[ct], bq, zero, 0, 0, 0);
      float m = -1e30f;
#pragma unroll
      for (int ct = 0; ct < 8; ++ct) {
        S[ct][0] += bmc[ct][0]; S[ct][1] += bmc[ct][1];
        S[ct][2] += bmc[ct][2]; S[ct][3] += bmc[ct][3];
        m = fmaxf(m, fmaxf(fmaxf(S[ct][0], S[ct][1]), fmaxf(S[ct][2], S[ct][3])));
      }
      m = fmaxf(m, __shfl_xor(m, 16));
      m = fmaxf(m, __shfl_xor(m, 32));
      float s = 0.f;
#pragma unroll
      for (int ct = 0; ct < 8; ++ct) {
#pragma unroll
        for (int r2 = 0; r2 < 4; ++r2) { S[ct][r2] = __expf(S[ct][r2] - m); s += S[ct][r2]; }
      }
      s += __shfl_xor(s, 16);
      s += __shfl_xor(s, 32);
      float inv = 1.0f / s;
      float* adst = attnh + qt * 16 * 128;
      s16x8 pfrag[4];
#pragma unroll
      for (int half = 0; half < 2; ++half) {
        float* A = half ? aSt1 : aSt0;     // alternate buffers: no serial LDS reuse
#pragma unroll
        for (int cc = 0; cc < 4; ++cc) {
          int ct = half * 4 + cc;
          f32x4 pv = { S[ct][0] * inv, S[ct][1] * inv, S[ct][2] * inv, S[ct][3] * inv };
          *(f32x4*)(A + lm * 68 + cc * 16 + lg * 4) = pv;
        }
#pragma unroll
        for (int i = 0; i < 4; ++i) {
          int o = l * 4 + i * 256;
          int row = o >> 6, col = o & 63;
          f32x4 v = *(const f32x4*)(A + row * 68 + col);
          __builtin_nontemporal_store(v, (f32x4*)(adst + row * 128 + half * 64 + col));
        }
#pragma unroll
        for (int k2 = 0; k2 < 2; ++k2) {
          const float* pp = A + lm * 68 + k2 * 32 + lg * 8;
          pfrag[half * 2 + k2] = cvt8(*(const f32x4*)pp, *(const f32x4*)(pp + 4));
        }
      }
      f32x4 O[2];
      O[0] = zero; O[1] = zero;
#pragma unroll
      for (int kk = 0; kk < 4; ++kk)
#pragma unroll
        for (int cd = 0; cd < 2; ++cd)
          O[cd] = __builtin_amdgcn_mfma_f32_16x16x32_bf16(av[kk * 2 + cd], pfrag[kk], O[cd], 0, 0, 0);
#pragma unroll
      for (int cd = 0; cd < 2; ++cd) {
        s16x4 pk;
#pragma unroll
        for (int r2 = 0; r2 < 4; ++r2) pk[r2] = (short)f2bf(O[cd][r2]);
        *(s16x4*)&XL[qt * 16 + lm][h * 32 + cd * 16 + lg * 4] = pk;
      }
    };
    body(0, bmA, bmB, true);
    body(1, bmB, bmA, true);
    body(2, bmA, bmB, true);
    body(3, bmB, bmA, false);
  }
  asm volatile("s_waitcnt lgkmcnt(0)" ::: "memory");
  __builtin_amdgcn_s_barrier();   // attn NT stores (vmcnt) keep draining under phase 3

  // ---- Phase 3: out-proj, wave w -> rows w*16..w*16+15 ----
  {
    float* aSt = scratch[w];
    f32x4 acc[8];
#pragma unroll
    for (int i = 0; i < 8; ++i) acc[i] = zero;
#pragma unroll
    for (int kk = 0; kk < 4; ++kk) {
      s16x8 a = *(const s16x8*)&XL[w * 16 + lm][kk * 32 + lg * 8];
#pragma unroll
      for (int ct = 0; ct < 8; ++ct) {
        s16x8 bf = *(const s16x8*)(pwb + (ct * 16 + lm) * 128 + kk * 32 + lg * 8);
        acc[ct] = __builtin_amdgcn_mfma_f32_16x16x32_bf16(a, bf, acc[ct], 0, 0, 0);
      }
    }
#pragma unroll
    for (int ct = 0; ct < 8; ++ct) {
      int col = ct * 16 + lm;
      float bb = pb[col];
#pragma unroll
      for (int r2 = 0; r2 < 4; ++r2) acc[ct][r2] += bb;
    }
    float* xdst = xout + ((size_t)b * 256 + q0 + w * 16) * 128;
#pragma unroll
    for (int half = 0; half < 2; ++half) {
      float* A = half ? (scratch[w] + 1088) : aSt;
#pragma unroll
      for (int cc = 0; cc < 4; ++cc) {
        int ct = half * 4 + cc;
#pragma unroll
        for (int r2 = 0; r2 < 4; ++r2)
          A[(lg * 4 + r2) * 68 + cc * 16 + lm] = acc[ct][r2];
      }
#pragma unroll
      for (int i = 0; i < 4; ++i) {
        int o = l * 4 + i * 256;
        int row = o >> 6, col = o & 63;
        f32x4 v = *(const f32x4*)(A + row * 68 + col);
        __builtin_nontemporal_store(v, (f32x4*)(xdst + row * 128 + half * 64 + col));
      }
    }
  }
}

extern "C" void kernel_launch(void* const* d_in, const int* in_sizes, int n_in,
                              void* d_out, int out_size, void* d_ws, size_t ws_size,
                              hipStream_t stream) {
  const float* q    = (const float*)d_in[0];
  const float* kv   = (const float*)d_in[1];
  const float* mask = (const float*)d_in[2];
  const float* qw   = (const float*)d_in[3];
  const float* qb   = (const float*)d_in[4];
  const float* kvw  = (const float*)d_in[5];
  const float* kvb  = (const float*)d_in[6];
  const float* pw   = (const float*)d_in[7];
  const float* pb   = (const float*)d_in[8];
  const float* rpb  = (const float*)d_in[9];
  const int* relidx = (const int*)d_in[10];

  float* xout = (float*)d_out;
  float* attn = xout + (size_t)1024 * 256 * 128;   // 33,554,432

  char* ws = (char*)d_ws;
  unsigned short* qwb  = (unsigned short*)ws;                 // 32 KB
  unsigned short* kvwb = (unsigned short*)(ws + 32768);       // 64 KB
  unsigned short* pwb  = (unsigned short*)(ws + 98304);       // 32 KB
  float*          bm   = (float*)(ws + 131072);               // 32 MB
  unsigned short* kws  = (unsigned short*)(ws + 131072 + 33554432);  // 32 MB
  unsigned short* vT   = kws + (size_t)16777216;              // 32 MB

  kw_prep<<<2048, 256, 0, stream>>>(qw, kvw, pw, rpb, relidx, mask, qwb, kvwb, pwb, bm);
  kkv<<<2048, 256, 0, stream>>>(kv, kvwb, kvb, kws, vT);
  kfused<<<4096, 256, 0, stream>>>(q, qwb, qb, kws, vT, bm, pwb, pb, attn, xout);
}